// Round 1
// baseline (444.759 us; speedup 1.0000x reference)
//
#include <hip/hip_runtime.h>
#include <cstdint>
#include <cstddef>

#define DEV static __device__ __forceinline__

typedef __attribute__((ext_vector_type(8))) short bf16x8_t;
typedef __attribute__((ext_vector_type(4))) float f32x4_t;

DEV unsigned short f2bf(float f) {
  union { float f; unsigned u; } v; v.f = f;
  unsigned r = v.u + 0x7fffu + ((v.u >> 16) & 1u);
  return (unsigned short)(r >> 16);
}

// async global->LDS, 16B per lane; LDS dest = wave-uniform base + lane*16
DEV void gl_lds16(const void* g, void* l) {
  __builtin_amdgcn_global_load_lds(
      (const __attribute__((address_space(1))) void*)g,
      (__attribute__((address_space(3))) void*)l,
      16, 0, 0);
}

// ---------------- prep: build_idx + casts + transposes, one launch --------
__global__ __launch_bounds__(256)
void prep_k(const int* __restrict__ target,
            int* __restrict__ idx1, int* __restrict__ pos1,
            int* __restrict__ idx2, int* __restrict__ pos2,
            int* __restrict__ cnts,
            const float* __restrict__ p0, const float* __restrict__ p1,
            const float* __restrict__ p2, unsigned short* __restrict__ pAll,
            const float* __restrict__ s0, unsigned short* __restrict__ d0, int n0,
            const float* __restrict__ s1, unsigned short* __restrict__ d1, int n1,
            const float* __restrict__ s2, unsigned short* __restrict__ d2, int n2,
            const float* __restrict__ s3, unsigned short* __restrict__ d3, int n3,
            const float* __restrict__ s4, unsigned short* __restrict__ d4, int n4) {
  const int bid = blockIdx.x;
  const int tid = threadIdx.x;
  if (bid == 0) {
    __shared__ int c1, c2;
    if (tid == 0) { c1 = 0; c2 = 0; }
    __syncthreads();
    for (int i = tid; i < 2048; i += 256) {
      int t = target[i];
      if (t >= 20000 && t < 50000) {
        int p = atomicAdd(&c1, 1); idx1[p] = i; pos1[i] = p;
      } else if (t >= 50000) {
        int p = atomicAdd(&c2, 1); idx2[p] = i; pos2[i] = p;
      }
    }
    __syncthreads();
    if (tid == 0) { cnts[0] = c1; cnts[1] = c2; }
    return;
  }
  if (bid <= 1344) {
    __shared__ float tile[32][33];
    int b = bid - 1;
    const float* src; unsigned short* dst; int C, bx, by;
    if (b < 1024)      { src = p0; dst = pAll;               C = 1024; bx = b % 32; by = b / 32; }
    else if (b < 1280) { int q = b - 1024; src = p1; dst = pAll + 1024 * 1024; C = 256; bx = q % 8; by = q / 8; }
    else               { int q = b - 1280; src = p2; dst = pAll + 1280 * 1024; C = 64;  bx = q % 2; by = q / 2; }
    const int R = 1024;
    int tx = tid & 31, ty = tid >> 5;
    int c0 = bx * 32, r0 = by * 32;
    for (int yy = ty; yy < 32; yy += 8)
      tile[yy][tx] = src[(size_t)(r0 + yy) * C + (c0 + tx)];
    __syncthreads();
    for (int yy = ty; yy < 32; yy += 8)
      dst[(size_t)(c0 + yy) * R + (r0 + tx)] = f2bf(tile[tx][yy]);
    return;
  }
  int j = (bid - 1345) * 256 + tid;
  const float* s; unsigned short* d;
  if (j < n0) { s = s0; d = d0; }
  else { j -= n0;
    if (j < n1) { s = s1; d = d1; }
    else { j -= n1;
      if (j < n2) { s = s2; d = d2; }
      else { j -= n2;
        if (j < n3) { s = s3; d = d3; }
        else { j -= n3; if (j >= n4) return; s = s4; d = d4; }
      }
    }
  }
  float4 f = ((const float4*)s)[j];
  ushort4 o;
  o.x = f2bf(f.x); o.y = f2bf(f.y); o.z = f2bf(f.z); o.w = f2bf(f.w);
  ((ushort4*)d)[j] = o;
}

// ---------------- proj GEMM: Pall[2048,1344] = Hb @ pAll^T ----------------
__global__ __launch_bounds__(256)
void proj_gemm_k(const unsigned short* __restrict__ A,
                 const unsigned short* __restrict__ W,
                 unsigned short* __restrict__ Cout) {
  __shared__ __align__(16) unsigned short As[128 * 32];
  __shared__ __align__(16) unsigned short Bs[128 * 32];
  const int K = 1024, V = 1344;
  const int tm = blockIdx.x, tn = blockIdx.y;
  const int m0 = tm * 128, n0 = tn * 128;
  const int tid = threadIdx.x, wid = tid >> 6, lane = tid & 63;
  const int quad = lane >> 4, l16 = lane & 15;
  const int wr = wid >> 1, wc = wid & 1;

  f32x4_t acc[4][4];
  const f32x4_t zero4 = {0.f, 0.f, 0.f, 0.f};
#pragma unroll
  for (int i = 0; i < 4; ++i)
#pragma unroll
    for (int j = 0; j < 4; ++j) acc[i][j] = zero4;

  const int srow = wid * 32 + (lane >> 2);
  const int skk  = (lane & 3) * 8;
  const unsigned short* Ap0 = A + (size_t)(m0 + srow) * K + skk;
  const unsigned short* Ap1 = A + (size_t)(m0 + srow + 16) * K + skk;
  int wrow0 = n0 + srow;      if (wrow0 > V - 1) wrow0 = V - 1;
  int wrow1 = n0 + srow + 16; if (wrow1 > V - 1) wrow1 = V - 1;
  const unsigned short* Wp0 = W + (size_t)wrow0 * K + skk;
  const unsigned short* Wp1 = W + (size_t)wrow1 * K + skk;
  unsigned short* Asw = As + wid * 1024;
  unsigned short* Bsw = Bs + wid * 1024;

  for (int k0 = 0; k0 < K; k0 += 32) {
    gl_lds16(Ap0, Asw);
    gl_lds16(Ap1, Asw + 512);
    gl_lds16(Wp0, Bsw);
    gl_lds16(Wp1, Bsw + 512);
    Ap0 += 32; Ap1 += 32; Wp0 += 32; Wp1 += 32;
    __syncthreads();
    bf16x8_t af[4], bfr[4];
#pragma unroll
    for (int i = 0; i < 4; ++i)
      af[i] = *(const bf16x8_t*)(As + (size_t)(wr * 64 + i * 16 + l16) * 32 + quad * 8);
#pragma unroll
    for (int j = 0; j < 4; ++j)
      bfr[j] = *(const bf16x8_t*)(Bs + (size_t)(wc * 64 + j * 16 + l16) * 32 + quad * 8);
#pragma unroll
    for (int i = 0; i < 4; ++i)
#pragma unroll
      for (int j = 0; j < 4; ++j)
        acc[i][j] = __builtin_amdgcn_mfma_f32_16x16x32_bf16(af[i], bfr[j], acc[i][j], 0, 0, 0);
    __syncthreads();
  }
#pragma unroll
  for (int i = 0; i < 4; ++i)
#pragma unroll
    for (int j = 0; j < 4; ++j) {
      const int n = n0 + wc * 64 + j * 16 + l16;
      if (n < V) {
#pragma unroll
        for (int r = 0; r < 4; ++r) {
          const int m = m0 + wr * 64 + i * 16 + quad * 4 + r;
          Cout[(size_t)m * V + n] = f2bf(acc[i][j][r]);
        }
      }
    }
}

// ---------------- head GEMM: 256x256 8-phase pipelined template -----------
// M=2048 N=20002(pad 20224) K=1024. BM=BN=256 BK=64, 512 thr = 8 waves (2x4),
// per-wave C = 128x64 (acc[8][4]). LDS = 2dbuf x (A 256x64 + B 256x64) bf16
// = 128 KiB, staged in 128-row halves (2 x gl_lds16 per thread per half).
// st_16x32 swizzle: phys = logical ^ ((logical>>9)&1)<<5, applied as
// inverse-swizzled GLOBAL source (gl_lds dest stays linear) + swizzled
// ds_read address. 4 phases per K-tile, each: {ds_read subtile | stage 1
// half-tile -> barrier -> lgkmcnt(0) -> setprio(1) 16xMFMA setprio(0) ->
// barrier}. ONE counted vmcnt(4) per K-tile (2 half-tiles = 4 loads stay in
// flight across barriers; never drains to 0 in the loop). Stage schedule per
// K-tile kt (buf d=kt&1, e=d^1): q0 B1(kt+1)->e, q1 A1(kt+1)->e,
// q2 B0(kt+2)->d, q3 A0(kt+2)->d; targets clamped to tile 15 at the tail so
// vmcnt counts stay uniform (redundant writes land in dead buffers).
// All epilogue global loads (bias/target) kept after the loop so no stray
// vmem op perturbs the vmcnt arithmetic.

#define SBAR()                                                                \
  __builtin_amdgcn_sched_barrier(0);                                          \
  __builtin_amdgcn_s_barrier();                                               \
  __builtin_amdgcn_sched_barrier(0)

#define LGKM0()                                                               \
  asm volatile("s_waitcnt lgkmcnt(0)" ::: "memory");                          \
  __builtin_amdgcn_sched_barrier(0)

#define STA(BUF, HALF, KT)                                                    \
  {                                                                           \
    const unsigned short* g_ = aB0 + (size_t)(HALF) * (128 * 1344) + (KT) * 64; \
    char* d_ = (char*)SA[BUF][HALF] + ldsw;                                   \
    gl_lds16(g_, d_);                                                         \
    gl_lds16(g_ + 64 * 1344, d_ + 8192);                                      \
  }

#define STB(BUF, HALF, KT)                                                    \
  {                                                                           \
    char* d_ = (char*)SB[BUF][HALF] + ldsw;                                   \
    gl_lds16(bP##HALF##0 + (KT) * 64, d_);                                    \
    gl_lds16(bP##HALF##1 + (KT) * 64, d_ + 8192);                             \
  }

#define MM16(mb, nb)                                                          \
  {                                                                           \
    _Pragma("unroll") for (int mi = 0; mi < 4; ++mi) {                        \
      _Pragma("unroll") for (int nj = 0; nj < 2; ++nj) {                      \
        acc[(mb) + mi][(nb) + nj] = __builtin_amdgcn_mfma_f32_16x16x32_bf16(  \
            Af[0][mi], Bf[(nb) / 2][0][nj], acc[(mb) + mi][(nb) + nj], 0, 0, 0); \
        acc[(mb) + mi][(nb) + nj] = __builtin_amdgcn_mfma_f32_16x16x32_bf16(  \
            Af[1][mi], Bf[(nb) / 2][1][nj], acc[(mb) + mi][(nb) + nj], 0, 0, 0); \
      }                                                                       \
    }                                                                         \
  }

#define PH(D_, E_, KTV)                                                       \
  {                                                                           \
    const int kt_ = (KTV);                                                    \
    const int t1_ = (kt_ + 1 > 15) ? 15 : (kt_ + 1);                          \
    const int t2_ = (kt_ + 2 > 15) ? 15 : (kt_ + 2);                          \
    /* q0: ds_read A(m0-3)+B(n0-1); stage B1(kt+1) */                         \
    _Pragma("unroll") for (int kk = 0; kk < 2; ++kk) {                        \
      _Pragma("unroll") for (int mi = 0; mi < 4; ++mi)                        \
          Af[kk][mi] = *(const bf16x8_t*)(pa##D_ + mi * 2048 + kk * 64);      \
      _Pragma("unroll") for (int nj = 0; nj < 2; ++nj)                        \
          Bf[0][kk][nj] = *(const bf16x8_t*)(pb##D_ + nj * 2048 + kk * 64);   \
    }                                                                         \
    STB(E_, 1, t1_);                                                          \
    SBAR();                                                                   \
    LGKM0();                                                                  \
    __builtin_amdgcn_s_setprio(1);                                            \
    MM16(0, 0);                                                               \
    __builtin_amdgcn_s_setprio(0);                                            \
    SBAR();                                                                   \
    /* q1: ds_read B(n2-3); stage A1(kt+1) */                                 \
    _Pragma("unroll") for (int kk = 0; kk < 2; ++kk) {                        \
      _Pragma("unroll") for (int nj = 0; nj < 2; ++nj)                        \
          Bf[1][kk][nj] = *(const bf16x8_t*)(pb##D_ + (2 + nj) * 2048 + kk * 64); \
    }                                                                         \
    STA(E_, 1, t1_);                                                          \
    SBAR();                                                                   \
    LGKM0();                                                                  \
    __builtin_amdgcn_s_setprio(1);                                            \
    MM16(0, 2);                                                               \
    __builtin_amdgcn_s_setprio(0);                                            \
    SBAR();                                                                   \
    /* q2: ds_read A(m4-7); stage B0(kt+2) */                                 \
    _Pragma("unroll") for (int kk = 0; kk < 2; ++kk) {                        \
      _Pragma("unroll") for (int mi = 0; mi < 4; ++mi)                        \
          Af[kk][mi] = *(const bf16x8_t*)(pa##D_ + (4 + mi) * 2048 + kk * 64); \
    }                                                                         \
    STB(D_, 0, t2_);                                                          \
    SBAR();                                                                   \
    LGKM0();                                                                  \
    __builtin_amdgcn_s_setprio(1);                                            \
    MM16(4, 0);                                                               \
    __builtin_amdgcn_s_setprio(0);                                            \
    SBAR();                                                                   \
    /* q3: stage A0(kt+2); counted vmcnt(4) once per K-tile */                \
    STA(D_, 0, t2_);                                                          \
    SBAR();                                                                   \
    __builtin_amdgcn_s_setprio(1);                                            \
    MM16(4, 2);                                                               \
    __builtin_amdgcn_s_setprio(0);                                            \
    asm volatile("s_waitcnt vmcnt(4)" ::: "memory");                          \
    SBAR();                                                                   \
  }

__global__ __launch_bounds__(512, 2)
void head256_k(const unsigned short* __restrict__ Pall,
               const unsigned short* __restrict__ w0b,
               const float* __restrict__ b0, const float* __restrict__ cb,
               float* __restrict__ part0, float* __restrict__ g0,
               float* __restrict__ cg, const int* __restrict__ target) {
  __shared__ __align__(16) unsigned short SA[2][2][8192];  // [dbuf][half][128*64]
  __shared__ __align__(16) unsigned short SB[2][2][8192];

  const int V = 20002;
  // XCD swizzle: 632 blocks % 8 == 0 -> simple bijection; stripe-major so
  // each XCD's L2 holds ~10 consecutive W-stripes (~5 MB).
  const int bid = blockIdx.x;
  const int orig = (bid & 7) * 79 + (bid >> 3);
  const int mt = orig & 7, stripe = orig >> 3;
  const int m0 = mt * 256, n0 = stripe * 256;

  const int tid = threadIdx.x;
  const int wid = tid >> 6, lane = tid & 63;
  const int quad = lane >> 4, l16 = lane & 15;
  const int wr = wid >> 2, wc = wid & 3;

  // staging source decode: thread fills phys bytes {tid*16, 8192+tid*16} of a
  // 16KB half-tile; inverse-swizzle gives the logical (row,col) to fetch.
  const int P0v = tid * 16;
  const int Ls = P0v ^ (((P0v >> 9) & 1) << 5);
  const int r0 = Ls >> 7;          // 0..63 (second chunk = +64 rows)
  const int ibh = (Ls & 127) >> 1; // element col 0..63

  const unsigned short* aB0 = Pall + (size_t)(m0 + r0) * 1344 + ibh;
  int br00 = n0 + r0;            if (br00 > V - 1) br00 = V - 1;
  int br01 = n0 + r0 + 64;       if (br01 > V - 1) br01 = V - 1;
  int br10 = n0 + 128 + r0;      if (br10 > V - 1) br10 = V - 1;
  int br11 = n0 + 128 + r0 + 64; if (br11 > V - 1) br11 = V - 1;
  const unsigned short* bP00 = w0b + (size_t)br00 * 1024 + ibh;
  const unsigned short* bP01 = w0b + (size_t)br01 * 1024 + ibh;
  const unsigned short* bP10 = w0b + (size_t)br10 * 1024 + ibh;
  const unsigned short* bP11 = w0b + (size_t)br11 * 1024 + ibh;

  const int ldsw = wid * 1024;  // wave-uniform gl_lds dest base

  // swizzled ds_read lane offset (bit9 of logical byte == l16 bit2)
  const int aoff = (l16 * 128 + quad * 16) ^ (((l16 >> 2) & 1) << 5);
  const char* pa0 = (const char*)SA[0][wr] + aoff;
  const char* pa1 = (const char*)SA[1][wr] + aoff;
  const char* pb0 = (const char*)SB[0][wc >> 1] + (wc & 1) * 8192 + aoff;
  const char* pb1 = (const char*)SB[1][wc >> 1] + (wc & 1) * 8192 + aoff;

  f32x4_t acc[8][4];
  const f32x4_t zero4 = {0.f, 0.f, 0.f, 0.f};
#pragma unroll
  for (int i = 0; i < 8; ++i)
#pragma unroll
    for (int j = 0; j < 4; ++j) acc[i][j] = zero4;

  bf16x8_t Af[2][4];     // [kk][m-frag of current m-half]
  bf16x8_t Bf[2][2][2];  // [n-half][kk][n-frag]

  // prologue: kt0 all 4 half-tiles + kt1 {B0,A0}; vmcnt(4) -> kt0 landed.
  STB(0, 0, 0); STA(0, 0, 0); STB(0, 1, 0); STA(0, 1, 0);
  STB(1, 0, 1); STA(1, 0, 1);
  asm volatile("s_waitcnt vmcnt(4)" ::: "memory");
  SBAR();

#pragma unroll 1
  for (int ktp = 0; ktp < 8; ++ktp) {
    const int kt0 = 2 * ktp;
    PH(0, 1, kt0);
    PH(1, 0, kt0 + 1);
  }

  // drain all staging before LDS reuse
  asm volatile("s_waitcnt vmcnt(0)" ::: "memory");
  SBAR();

  int nj[4]; float bj[4];
#pragma unroll
  for (int j = 0; j < 4; ++j) {
    nj[j] = n0 + wc * 64 + j * 16 + l16;
    bj[j] = (nj[j] < 20000) ? b0[nj[j]] : ((nj[j] < V) ? cb[nj[j] - 20000] : 0.f);
  }
  float* redf = (float*)&SA[0][0][0];  // 8 x 128 floats
#pragma unroll
  for (int i = 0; i < 8; ++i) {
#pragma unroll
    for (int r = 0; r < 4; ++r) {
      const int rloc = i * 16 + quad * 4 + r;  // 0..127 within wave's half
      const int token = m0 + wr * 128 + rloc;
      float v[4], sum = 0.f;
#pragma unroll
      for (int j = 0; j < 4; ++j) {
        v[j] = acc[i][j][r] + bj[j];
        if (nj[j] < V) sum += __expf(v[j]);
      }
#pragma unroll
      for (int off = 1; off < 16; off <<= 1)
        sum += __shfl_xor(sum, off, 64);
      if (l16 == 0) redf[(wr * 4 + wc) * 128 + rloc] = sum;
      const int t = target[token];
      const int gi = (t < 19999) ? t : 19999;
#pragma unroll
      for (int j = 0; j < 4; ++j) {
        if (nj[j] == gi) g0[token] = v[j];
        if (nj[j] == 20000) cg[2 * token]     = v[j];
        if (nj[j] == 20001) cg[2 * token + 1] = v[j];
      }
    }
  }
  __syncthreads();
  if (tid < 256) {
    const int wrr = tid >> 7, rr = tid & 127;
    const float s = redf[(wrr * 4 + 0) * 128 + rr] + redf[(wrr * 4 + 1) * 128 + rr]
                  + redf[(wrr * 4 + 2) * 128 + rr] + redf[(wrr * 4 + 3) * 128 + rr];
    part0[(size_t)(m0 + tid) * 79 + stripe] = s;
  }
}

#undef PH
#undef MM16
#undef STA
#undef STB
#undef SBAR
#undef LGKM0

// ---------------- stripe-persistent tail GEMM -----------------------------
template <int KT>
__global__ __launch_bounds__(256, 1)
void tail_stripe_k(const unsigned short* __restrict__ A, int ldA,
                   const unsigned short* __restrict__ W,
                   const float* __restrict__ bias, int V, int ntiles,
                   const int* __restrict__ rowidx,
                   const int* __restrict__ cnt_ptr,
                   float* __restrict__ partials,
                   float* __restrict__ gathered,
                   const int* __restrict__ target, int glo) {
  constexpr int NC = KT / 32;
  __shared__ __align__(16) unsigned short Ws[NC][128 * 32];
  __shared__ __align__(16) unsigned short As[NC][128 * 32];
  __shared__ float red[2][128];

  const int tn = blockIdx.x, n0 = tn * 128;
  const int Meff = *cnt_ptr;
  const int tid = threadIdx.x, wid = tid >> 6, lane = tid & 63;
  const int quad = lane >> 4, l16 = lane & 15;
  const int wr = wid >> 1, wc = wid & 1;
  const int srow = wid * 32 + (lane >> 2);
  const int skk  = (lane & 3) * 8;

  int wrow0 = n0 + srow;      if (wrow0 > V - 1) wrow0 = V - 1;
  int wrow1 = n0 + srow + 16; if (wrow1 > V - 1) wrow1 = V - 1;
#pragma unroll
  for (int c = 0; c < NC; ++c) {
    gl_lds16(W + (size_t)wrow0 * KT + c * 32 + skk, Ws[c] + wid * 1024);
    gl_lds16(W + (size_t)wrow1 * KT + c * 32 + skk, Ws[c] + wid * 1024 + 512);
  }

  int nj[4]; float bj[4];
#pragma unroll
  for (int j = 0; j < 4; ++j) {
    nj[j] = n0 + wc * 64 + j * 16 + l16;
    bj[j] = (nj[j] < V) ? bias[nj[j]] : 0.f;
  }

  const int nm = (Meff + 127) >> 7;
  for (int m = 0; m < nm; ++m) {
    const int m0 = m * 128;
    int ar0 = m0 + srow;      if (ar0 > Meff - 1) ar0 = Meff - 1;
    int ar1 = m0 + srow + 16; if (ar1 > Meff - 1) ar1 = Meff - 1;
    ar0 = rowidx[ar0]; ar1 = rowidx[ar1];
#pragma unroll
    for (int c = 0; c < NC; ++c) {
      gl_lds16(A + (size_t)ar0 * ldA + c * 32 + skk, As[c] + wid * 1024);
      gl_lds16(A + (size_t)ar1 * ldA + c * 32 + skk, As[c] + wid * 1024 + 512);
    }
    __syncthreads();

    f32x4_t acc[4][4];
    const f32x4_t zero4 = {0.f, 0.f, 0.f, 0.f};
#pragma unroll
    for (int i = 0; i < 4; ++i)
#pragma unroll
      for (int j = 0; j < 4; ++j) acc[i][j] = zero4;
#pragma unroll
    for (int c = 0; c < NC; ++c) {
      bf16x8_t af[4], bfr[4];
#pragma unroll
      for (int i = 0; i < 4; ++i)
        af[i] = *(const bf16x8_t*)(As[c] + (size_t)(wr * 64 + i * 16 + l16) * 32 + quad * 8);
#pragma unroll
      for (int j = 0; j < 4; ++j)
        bfr[j] = *(const bf16x8_t*)(Ws[c] + (size_t)(wc * 64 + j * 16 + l16) * 32 + quad * 8);
#pragma unroll
      for (int i = 0; i < 4; ++i)
#pragma unroll
        for (int j = 0; j < 4; ++j)
          acc[i][j] = __builtin_amdgcn_mfma_f32_16x16x32_bf16(af[i], bfr[j], acc[i][j], 0, 0, 0);
    }

#pragma unroll
    for (int i = 0; i < 4; ++i) {
#pragma unroll
      for (int r = 0; r < 4; ++r) {
        const int row = wr * 64 + i * 16 + quad * 4 + r;
        const int gr = m0 + row;
        const int grc = (gr < Meff) ? gr : (Meff - 1);
        const int token = rowidx[grc];
        float v[4], sum = 0.f;
#pragma unroll
        for (int j = 0; j < 4; ++j) {
          v[j] = acc[i][j][r] + bj[j];
          if (nj[j] < V) sum += __expf(v[j]);
        }
#pragma unroll
        for (int off = 1; off < 16; off <<= 1)
          sum += __shfl_xor(sum, off, 64);
        if (l16 == 0) red[wc][row] = sum;
        const int gi = target[token] - glo;
#pragma unroll
        for (int j = 0; j < 4; ++j)
          if (nj[j] == gi) gathered[token] = v[j];
      }
    }
    __syncthreads();
    if (tid < 128 && (m0 + tid) < Meff)
      partials[(size_t)(m0 + tid) * ntiles + tn] = red[0][tid] + red[1][tid];
  }
}

// ---------------- combine: wave per token ----------------
__global__ __launch_bounds__(256)
void combine_k(const float* __restrict__ part0,
               const float* __restrict__ part1, int nt1,
               const float* __restrict__ part2, int nt2,
               const float* __restrict__ g0, const float* __restrict__ g1,
               const float* __restrict__ g2, const float* __restrict__ cg,
               const int* __restrict__ pos1, const int* __restrict__ pos2,
               const int* __restrict__ target, float* __restrict__ out) {
  const int w = threadIdx.x >> 6, lane = threadIdx.x & 63;
  const int token = blockIdx.x * 4 + w;
  const int t = target[token];

  float S = 0.f;
  for (int i = lane; i < 79; i += 64)
    S += part0[(size_t)token * 79 + i];
#pragma unroll
  for (int off = 1; off < 64; off <<= 1)
    S += __shfl_xor(S, off, 64);
  const float lse_head = __logf(S);

  float res;
  if (t < 20000) {
    res = lse_head - g0[token];
  } else {
    const float* pt; int nt; float gv, ch; int row;
    if (t < 50000) { pt = part1; nt = nt1; gv = g1[token]; ch = cg[2 * token + 1]; row = pos1[token]; }
    else           { pt = part2; nt = nt2; gv = g2[token]; ch = cg[2 * token];     row = pos2[token]; }
    float S2 = 0.f;
    for (int i = lane; i < nt; i += 64)
      S2 += pt[(size_t)row * nt + i];
#pragma unroll
    for (int off = 1; off < 64; off <<= 1)
      S2 += __shfl_xor(S2, off, 64);
    float lse_t = __logf(S2);
    res = -((ch - lse_head) + (gv - lse_t));
  }
  if (lane == 0) out[token] = res;
}

extern "C" void kernel_launch(void* const* d_in, const int* in_sizes, int n_in,
                              void* d_out, int out_size, void* d_ws, size_t ws_size,
                              hipStream_t stream) {
  (void)in_sizes; (void)n_in; (void)out_size; (void)ws_size;
  const float* hidden = (const float*)d_in[0];
  const int*   target = (const int*)d_in[1];
  const float* w0     = (const float*)d_in[2];
  const float* b0     = (const float*)d_in[3];
  const float* cw     = (const float*)d_in[4];
  const float* cb     = (const float*)d_in[5];
  const float* proj0  = (const float*)d_in[6];
  const float* w1     = (const float*)d_in[7];
  const float* b1     = (const float*)d_in[8];
  const float* proj1  = (const float*)d_in[9];
  const float* w2     = (const float*)d_in[10];
  const float* b2     = (const float*)d_in[11];
  const float* proj2  = (const float*)d_in[12];
  float* out = (float*)d_out;

  const int NT1 = 235, NT2 = 391;

  char* p = (char*)d_ws;
  auto alloc = [&](size_t bytes) {
    char* r = p; p += (bytes + 255) & ~(size_t)255; return r;
  };
  unsigned short* Hb   = (unsigned short*)alloc(2048ull * 1024 * 2);
  unsigned short* pAll = (unsigned short*)alloc(1344ull * 1024 * 2);
  unsigned short* w0b  = (unsigned short*)alloc(20002ull * 1024 * 2);
  unsigned short* w1b  = (unsigned short*)alloc(30000ull * 256 * 2);
  unsigned short* w2b  = (unsigned short*)alloc(50000ull * 64 * 2);
  unsigned short* Pall = (unsigned short*)alloc(2048ull * 1344 * 2);
  float* part0 = (float*)alloc(2048ull * 79 * 4);
  float* part1 = (float*)alloc(2048ull * NT1 * 4);
  float* part2 = (float*)alloc(2048ull * NT2 * 4);
  float* g0 = (float*)alloc(2048 * 4);
  float* g1 = (float*)alloc(2048 * 4);
  float* g2 = (float*)alloc(2048 * 4);
  float* cg = (float*)alloc(2048 * 2 * 4);
  int* idx1 = (int*)alloc(2048 * 4);
  int* pos1 = (int*)alloc(2048 * 4);
  int* idx2 = (int*)alloc(2048 * 4);
  int* pos2 = (int*)alloc(2048 * 4);
  int* cnts = (int*)alloc(2 * 4);

  const int c_h = 2048 * 1024 / 4, c_w0 = 20000 * 1024 / 4, c_cw = 2048 / 4,
            c_w1 = 30000 * 256 / 4, c_w2 = 50000 * 64 / 4;
  const int ctot = c_h + c_w0 + c_cw + c_w1 + c_w2;
  const int nb_cast = (ctot + 255) / 256;
  prep_k<<<1 + 1344 + nb_cast, 256, 0, stream>>>(
      target, idx1, pos1, idx2, pos2, cnts,
      proj0, proj1, proj2, pAll,
      hidden, Hb, c_h,
      w0, w0b, c_w0,
      cw, w0b + 20000ull * 1024, c_cw,
      w1, w1b, c_w1,
      w2, w2b, c_w2);

  // merged projections: Pall[2048,1344] = Hb @ pAll^T
  proj_gemm_k<<<dim3(16, 11), 256, 0, stream>>>(Hb, pAll, Pall);

  // head: 256^2 8-phase pipelined GEMM, grid = 8 m-tiles x 79 stripes
  head256_k<<<632, 512, 0, stream>>>(Pall, w0b, b0, cb, part0, g0, cg, target);

  // tails: one block per stripe, W persistent in LDS, m-loop inside
  tail_stripe_k<256><<<NT1, 256, 0, stream>>>(
      Pall + 1024, 1344, w1b, b1, 30000, NT1, idx1, cnts + 0,
      part1, g1, target, 20000);
  tail_stripe_k<64><<<NT2, 256, 0, stream>>>(
      Pall + 1280, 1344, w2b, b2, 50000, NT2, idx2, cnts + 1,
      part2, g2, target, 50000);

  combine_k<<<512, 256, 0, stream>>>(part0, part1, NT1, part2, NT2,
      g0, g1, g2, cg, pos1, pos2, target, out);
}

// Round 2
// 428.404 us; speedup vs baseline: 1.0382x; 1.0382x over previous
//
#include <hip/hip_runtime.h>
#include <cstdint>
#include <cstddef>

#define DEV static __device__ __forceinline__

typedef __attribute__((ext_vector_type(8))) short bf16x8_t;
typedef __attribute__((ext_vector_type(4))) float f32x4_t;

DEV unsigned short f2bf(float f) {
  union { float f; unsigned u; } v; v.f = f;
  unsigned r = v.u + 0x7fffu + ((v.u >> 16) & 1u);
  return (unsigned short)(r >> 16);
}

// async global->LDS, 16B per lane; LDS dest = wave-uniform base + lane*16
DEV void gl_lds16(const void* g, void* l) {
  __builtin_amdgcn_global_load_lds(
      (const __attribute__((address_space(1))) void*)g,
      (__attribute__((address_space(3))) void*)l,
      16, 0, 0);
}

// ---------------- prep: build_idx + casts + transposes, one launch --------
__global__ __launch_bounds__(256)
void prep_k(const int* __restrict__ target,
            int* __restrict__ idx1, int* __restrict__ pos1,
            int* __restrict__ idx2, int* __restrict__ pos2,
            int* __restrict__ cnts,
            const float* __restrict__ p0, const float* __restrict__ p1,
            const float* __restrict__ p2, unsigned short* __restrict__ pAll,
            const float* __restrict__ s0, unsigned short* __restrict__ d0, int n0,
            const float* __restrict__ s1, unsigned short* __restrict__ d1, int n1,
            const float* __restrict__ s2, unsigned short* __restrict__ d2, int n2,
            const float* __restrict__ s3, unsigned short* __restrict__ d3, int n3,
            const float* __restrict__ s4, unsigned short* __restrict__ d4, int n4) {
  const int bid = blockIdx.x;
  const int tid = threadIdx.x;
  if (bid == 0) {
    __shared__ int c1, c2;
    if (tid == 0) { c1 = 0; c2 = 0; }
    __syncthreads();
    for (int i = tid; i < 2048; i += 256) {
      int t = target[i];
      if (t >= 20000 && t < 50000) {
        int p = atomicAdd(&c1, 1); idx1[p] = i; pos1[i] = p;
      } else if (t >= 50000) {
        int p = atomicAdd(&c2, 1); idx2[p] = i; pos2[i] = p;
      }
    }
    __syncthreads();
    if (tid == 0) { cnts[0] = c1; cnts[1] = c2; }
    return;
  }
  if (bid <= 1344) {
    __shared__ float tile[32][33];
    int b = bid - 1;
    const float* src; unsigned short* dst; int C, bx, by;
    if (b < 1024)      { src = p0; dst = pAll;               C = 1024; bx = b % 32; by = b / 32; }
    else if (b < 1280) { int q = b - 1024; src = p1; dst = pAll + 1024 * 1024; C = 256; bx = q % 8; by = q / 8; }
    else               { int q = b - 1280; src = p2; dst = pAll + 1280 * 1024; C = 64;  bx = q % 2; by = q / 2; }
    const int R = 1024;
    int tx = tid & 31, ty = tid >> 5;
    int c0 = bx * 32, r0 = by * 32;
    for (int yy = ty; yy < 32; yy += 8)
      tile[yy][tx] = src[(size_t)(r0 + yy) * C + (c0 + tx)];
    __syncthreads();
    for (int yy = ty; yy < 32; yy += 8)
      dst[(size_t)(c0 + yy) * R + (r0 + tx)] = f2bf(tile[tx][yy]);
    return;
  }
  int j = (bid - 1345) * 256 + tid;
  const float* s; unsigned short* d;
  if (j < n0) { s = s0; d = d0; }
  else { j -= n0;
    if (j < n1) { s = s1; d = d1; }
    else { j -= n1;
      if (j < n2) { s = s2; d = d2; }
      else { j -= n2;
        if (j < n3) { s = s3; d = d3; }
        else { j -= n3; if (j >= n4) return; s = s4; d = d4; }
      }
    }
  }
  float4 f = ((const float4*)s)[j];
  ushort4 o;
  o.x = f2bf(f.x); o.y = f2bf(f.y); o.z = f2bf(f.z); o.w = f2bf(f.w);
  ((ushort4*)d)[j] = o;
}

// ---------------- proj GEMM: Pall[2048,1344] = Hb @ pAll^T ----------------
__global__ __launch_bounds__(256)
void proj_gemm_k(const unsigned short* __restrict__ A,
                 const unsigned short* __restrict__ W,
                 unsigned short* __restrict__ Cout) {
  __shared__ __align__(16) unsigned short As[128 * 32];
  __shared__ __align__(16) unsigned short Bs[128 * 32];
  const int K = 1024, V = 1344;
  const int tm = blockIdx.x, tn = blockIdx.y;
  const int m0 = tm * 128, n0 = tn * 128;
  const int tid = threadIdx.x, wid = tid >> 6, lane = tid & 63;
  const int quad = lane >> 4, l16 = lane & 15;
  const int wr = wid >> 1, wc = wid & 1;

  f32x4_t acc[4][4];
  const f32x4_t zero4 = {0.f, 0.f, 0.f, 0.f};
#pragma unroll
  for (int i = 0; i < 4; ++i)
#pragma unroll
    for (int j = 0; j < 4; ++j) acc[i][j] = zero4;

  const int srow = wid * 32 + (lane >> 2);
  const int skk  = (lane & 3) * 8;
  const unsigned short* Ap0 = A + (size_t)(m0 + srow) * K + skk;
  const unsigned short* Ap1 = A + (size_t)(m0 + srow + 16) * K + skk;
  int wrow0 = n0 + srow;      if (wrow0 > V - 1) wrow0 = V - 1;
  int wrow1 = n0 + srow + 16; if (wrow1 > V - 1) wrow1 = V - 1;
  const unsigned short* Wp0 = W + (size_t)wrow0 * K + skk;
  const unsigned short* Wp1 = W + (size_t)wrow1 * K + skk;
  unsigned short* Asw = As + wid * 1024;
  unsigned short* Bsw = Bs + wid * 1024;

  for (int k0 = 0; k0 < K; k0 += 32) {
    gl_lds16(Ap0, Asw);
    gl_lds16(Ap1, Asw + 512);
    gl_lds16(Wp0, Bsw);
    gl_lds16(Wp1, Bsw + 512);
    Ap0 += 32; Ap1 += 32; Wp0 += 32; Wp1 += 32;
    __syncthreads();
    bf16x8_t af[4], bfr[4];
#pragma unroll
    for (int i = 0; i < 4; ++i)
      af[i] = *(const bf16x8_t*)(As + (size_t)(wr * 64 + i * 16 + l16) * 32 + quad * 8);
#pragma unroll
    for (int j = 0; j < 4; ++j)
      bfr[j] = *(const bf16x8_t*)(Bs + (size_t)(wc * 64 + j * 16 + l16) * 32 + quad * 8);
#pragma unroll
    for (int i = 0; i < 4; ++i)
#pragma unroll
      for (int j = 0; j < 4; ++j)
        acc[i][j] = __builtin_amdgcn_mfma_f32_16x16x32_bf16(af[i], bfr[j], acc[i][j], 0, 0, 0);
    __syncthreads();
  }
#pragma unroll
  for (int i = 0; i < 4; ++i)
#pragma unroll
    for (int j = 0; j < 4; ++j) {
      const int n = n0 + wc * 64 + j * 16 + l16;
      if (n < V) {
#pragma unroll
        for (int r = 0; r < 4; ++r) {
          const int m = m0 + wr * 64 + i * 16 + quad * 4 + r;
          Cout[(size_t)m * V + n] = f2bf(acc[i][j][r]);
        }
      }
    }
}

// ---------------- head GEMM: 256x256 8-phase pipelined template -----------
// As R1 but with FULL-RANK LDS swizzle: phys 16B-slot = col16 ^ (row&7)
// (R1's single-bit XOR left reads on 4 of 8 slots -> 2x bank serialization,
// 7.8M conflict cycles). Staging inverse: thread tid fills phys slot tid&7
// of phys row tid>>3 -> fetches logical col ((tid&7)^((tid>>3)&7))*8.
// ds_read: aoff0 = l16*128 + ((quad^(l16&3))<<4) + (((l16>>2)&1)<<6);
// kk=1 address = aoff0 ^ 64 (col16 bit2 = kk^bit2(row)).
// Read schedule rebalanced 12/4/8/0 -> Bf-hi issued right after q0's MFMA,
// Af-hi right after q1's MFMA (WAR-safe: Af regs last used by q1 MFMA;
// overwrite-safe: every stage into a region is issued only after a barrier
// all waves reached post-lgkmcnt(0) on that region's reads).
// vmcnt protocol unchanged (verified correct in R1).

#define SBAR()                                                                \
  __builtin_amdgcn_sched_barrier(0);                                          \
  __builtin_amdgcn_s_barrier();                                               \
  __builtin_amdgcn_sched_barrier(0)

#define LGKM0()                                                               \
  asm volatile("s_waitcnt lgkmcnt(0)" ::: "memory");                          \
  __builtin_amdgcn_sched_barrier(0)

#define STA(BUF, HALF, KT)                                                    \
  {                                                                           \
    const unsigned short* g_ = aB0 + (size_t)(HALF) * (128 * 1344) + (KT) * 64; \
    char* d_ = (char*)SA[BUF][HALF] + ldsw;                                   \
    gl_lds16(g_, d_);                                                         \
    gl_lds16(g_ + 64 * 1344, d_ + 8192);                                      \
  }

#define STB(BUF, HALF, KT)                                                    \
  {                                                                           \
    char* d_ = (char*)SB[BUF][HALF] + ldsw;                                   \
    gl_lds16(bP##HALF##0 + (KT) * 64, d_);                                    \
    gl_lds16(bP##HALF##1 + (KT) * 64, d_ + 8192);                             \
  }

#define MM16(mb, nb)                                                          \
  {                                                                           \
    _Pragma("unroll") for (int mi = 0; mi < 4; ++mi) {                        \
      _Pragma("unroll") for (int nj = 0; nj < 2; ++nj) {                      \
        acc[(mb) + mi][(nb) + nj] = __builtin_amdgcn_mfma_f32_16x16x32_bf16(  \
            Af[0][mi], Bf[(nb) / 2][0][nj], acc[(mb) + mi][(nb) + nj], 0, 0, 0); \
        acc[(mb) + mi][(nb) + nj] = __builtin_amdgcn_mfma_f32_16x16x32_bf16(  \
            Af[1][mi], Bf[(nb) / 2][1][nj], acc[(mb) + mi][(nb) + nj], 0, 0, 0); \
      }                                                                       \
    }                                                                         \
  }

#define PH(D_, E_, KTV)                                                       \
  {                                                                           \
    const int kt_ = (KTV);                                                    \
    const int t1_ = (kt_ + 1 > 15) ? 15 : (kt_ + 1);                          \
    const int t2_ = (kt_ + 2 > 15) ? 15 : (kt_ + 2);                          \
    /* tile-top reads: Af-lo (8) + Bf-lo (4); stage B1(kt+1) */               \
    _Pragma("unroll") for (int mi = 0; mi < 4; ++mi) {                        \
      Af[0][mi] = *(const bf16x8_t*)(pa##D_##a + mi * 2048);                  \
      Af[1][mi] = *(const bf16x8_t*)(pa##D_##b + mi * 2048);                  \
    }                                                                         \
    _Pragma("unroll") for (int nj = 0; nj < 2; ++nj) {                        \
      Bf[0][0][nj] = *(const bf16x8_t*)(pb##D_##a + nj * 2048);               \
      Bf[0][1][nj] = *(const bf16x8_t*)(pb##D_##b + nj * 2048);               \
    }                                                                         \
    STB(E_, 1, t1_);                                                          \
    SBAR();                                                                   \
    LGKM0();                                                                  \
    __builtin_amdgcn_s_setprio(1);                                            \
    MM16(0, 0);                                                               \
    __builtin_amdgcn_s_setprio(0);                                            \
    /* early-issue Bf-hi (4) for q1 */                                        \
    _Pragma("unroll") for (int nj = 0; nj < 2; ++nj) {                        \
      Bf[1][0][nj] = *(const bf16x8_t*)(pb##D_##a + (2 + nj) * 2048);         \
      Bf[1][1][nj] = *(const bf16x8_t*)(pb##D_##b + (2 + nj) * 2048);         \
    }                                                                         \
    SBAR();                                                                   \
    STA(E_, 1, t1_);                                                          \
    SBAR();                                                                   \
    LGKM0();                                                                  \
    __builtin_amdgcn_s_setprio(1);                                            \
    MM16(0, 2);                                                               \
    __builtin_amdgcn_s_setprio(0);                                            \
    /* early-issue Af-hi (8) for q2/q3 (Af-lo regs dead after MM16(0,2)) */   \
    _Pragma("unroll") for (int mi = 0; mi < 4; ++mi) {                        \
      Af[0][mi] = *(const bf16x8_t*)(pa##D_##a + (4 + mi) * 2048);            \
      Af[1][mi] = *(const bf16x8_t*)(pa##D_##b + (4 + mi) * 2048);            \
    }                                                                         \
    SBAR();                                                                   \
    STB(D_, 0, t2_);                                                          \
    SBAR();                                                                   \
    LGKM0();                                                                  \
    __builtin_amdgcn_s_setprio(1);                                            \
    MM16(4, 0);                                                               \
    __builtin_amdgcn_s_setprio(0);                                            \
    SBAR();                                                                   \
    STA(D_, 0, t2_);                                                          \
    SBAR();                                                                   \
    __builtin_amdgcn_s_setprio(1);                                            \
    MM16(4, 2);                                                               \
    __builtin_amdgcn_s_setprio(0);                                            \
    asm volatile("s_waitcnt vmcnt(4)" ::: "memory");                          \
    SBAR();                                                                   \
  }

__global__ __launch_bounds__(512, 2)
void head256_k(const unsigned short* __restrict__ Pall,
               const unsigned short* __restrict__ w0b,
               const float* __restrict__ b0, const float* __restrict__ cb,
               float* __restrict__ part0, float* __restrict__ g0,
               float* __restrict__ cg, const int* __restrict__ target) {
  __shared__ __align__(16) unsigned short SA[2][2][8192];  // [dbuf][half][128*64]
  __shared__ __align__(16) unsigned short SB[2][2][8192];

  const int V = 20002;
  // XCD swizzle: 632 blocks % 8 == 0 -> simple bijection; stripe-major so
  // each XCD's L2 holds ~10 consecutive W-stripes (~5 MB).
  const int bid = blockIdx.x;
  const int orig = (bid & 7) * 79 + (bid >> 3);
  const int mt = orig & 7, stripe = orig >> 3;
  const int m0 = mt * 256, n0 = stripe * 256;

  const int tid = threadIdx.x;
  const int wid = tid >> 6, lane = tid & 63;
  const int quad = lane >> 4, l16 = lane & 15;
  const int wr = wid >> 2, wc = wid & 3;

  // staging source decode (full-rank swizzle inverse): thread fills phys
  // bytes {tid*16, 8192+tid*16}; phys row tid>>3, phys slot tid&7 ->
  // logical col16 = slot ^ (row&7).
  const int r0  = tid >> 3;                       // phys row 0..63
  const int ibh = ((tid & 7) ^ (r0 & 7)) << 3;    // logical element col

  const unsigned short* aB0 = Pall + (size_t)(m0 + r0) * 1344 + ibh;
  int br00 = n0 + r0;            if (br00 > V - 1) br00 = V - 1;
  int br01 = n0 + r0 + 64;       if (br01 > V - 1) br01 = V - 1;
  int br10 = n0 + 128 + r0;      if (br10 > V - 1) br10 = V - 1;
  int br11 = n0 + 128 + r0 + 64; if (br11 > V - 1) br11 = V - 1;
  const unsigned short* bP00 = w0b + (size_t)br00 * 1024 + ibh;
  const unsigned short* bP01 = w0b + (size_t)br01 * 1024 + ibh;
  const unsigned short* bP10 = w0b + (size_t)br10 * 1024 + ibh;
  const unsigned short* bP11 = w0b + (size_t)br11 * 1024 + ibh;

  const int ldsw = wid * 1024;  // wave-uniform gl_lds dest base

  // swizzled ds_read lane offsets: slot = (quad+4kk) ^ (l16&7)
  const int aoff0 = l16 * 128 + ((quad ^ (l16 & 3)) << 4) + (((l16 >> 2) & 1) << 6);
  const int aoff1 = aoff0 ^ 64;  // kk=1 flips col16 bit2
  const char* pa0a = (const char*)SA[0][wr] + aoff0;
  const char* pa0b = (const char*)SA[0][wr] + aoff1;
  const char* pa1a = (const char*)SA[1][wr] + aoff0;
  const char* pa1b = (const char*)SA[1][wr] + aoff1;
  const char* pb0a = (const char*)SB[0][wc >> 1] + (wc & 1) * 8192 + aoff0;
  const char* pb0b = (const char*)SB[0][wc >> 1] + (wc & 1) * 8192 + aoff1;
  const char* pb1a = (const char*)SB[1][wc >> 1] + (wc & 1) * 8192 + aoff0;
  const char* pb1b = (const char*)SB[1][wc >> 1] + (wc & 1) * 8192 + aoff1;

  f32x4_t acc[8][4];
  const f32x4_t zero4 = {0.f, 0.f, 0.f, 0.f};
#pragma unroll
  for (int i = 0; i < 8; ++i)
#pragma unroll
    for (int j = 0; j < 4; ++j) acc[i][j] = zero4;

  bf16x8_t Af[2][4];     // [kk][m-frag of current m-half]
  bf16x8_t Bf[2][2][2];  // [n-half][kk][n-frag]

  // prologue: kt0 all 4 half-tiles + kt1 {B0,A0}; vmcnt(4) -> kt0 landed.
  STB(0, 0, 0); STA(0, 0, 0); STB(0, 1, 0); STA(0, 1, 0);
  STB(1, 0, 1); STA(1, 0, 1);
  asm volatile("s_waitcnt vmcnt(4)" ::: "memory");
  SBAR();

#pragma unroll 1
  for (int ktp = 0; ktp < 8; ++ktp) {
    const int kt0 = 2 * ktp;
    PH(0, 1, kt0);
    PH(1, 0, kt0 + 1);
  }

  // drain all staging before LDS reuse
  asm volatile("s_waitcnt vmcnt(0)" ::: "memory");
  SBAR();

  int nj[4]; float bj[4];
#pragma unroll
  for (int j = 0; j < 4; ++j) {
    nj[j] = n0 + wc * 64 + j * 16 + l16;
    bj[j] = (nj[j] < 20000) ? b0[nj[j]] : ((nj[j] < V) ? cb[nj[j] - 20000] : 0.f);
  }
  float* redf = (float*)&SA[0][0][0];  // 8 x 128 floats
#pragma unroll
  for (int i = 0; i < 8; ++i) {
#pragma unroll
    for (int r = 0; r < 4; ++r) {
      const int rloc = i * 16 + quad * 4 + r;  // 0..127 within wave's half
      const int token = m0 + wr * 128 + rloc;
      float v[4], sum = 0.f;
#pragma unroll
      for (int j = 0; j < 4; ++j) {
        v[j] = acc[i][j][r] + bj[j];
        if (nj[j] < V) sum += __expf(v[j]);
      }
#pragma unroll
      for (int off = 1; off < 16; off <<= 1)
        sum += __shfl_xor(sum, off, 64);
      if (l16 == 0) redf[(wr * 4 + wc) * 128 + rloc] = sum;
      const int t = target[token];
      const int gi = (t < 19999) ? t : 19999;
#pragma unroll
      for (int j = 0; j < 4; ++j) {
        if (nj[j] == gi) g0[token] = v[j];
        if (nj[j] == 20000) cg[2 * token]     = v[j];
        if (nj[j] == 20001) cg[2 * token + 1] = v[j];
      }
    }
  }
  __syncthreads();
  if (tid < 256) {
    const int wrr = tid >> 7, rr = tid & 127;
    const float s = redf[(wrr * 4 + 0) * 128 + rr] + redf[(wrr * 4 + 1) * 128 + rr]
                  + redf[(wrr * 4 + 2) * 128 + rr] + redf[(wrr * 4 + 3) * 128 + rr];
    part0[(size_t)(m0 + tid) * 79 + stripe] = s;
  }
}

#undef PH
#undef MM16
#undef STA
#undef STB
#undef SBAR
#undef LGKM0

// ---------------- stripe-persistent tail GEMM -----------------------------
template <int KT>
__global__ __launch_bounds__(256, 1)
void tail_stripe_k(const unsigned short* __restrict__ A, int ldA,
                   const unsigned short* __restrict__ W,
                   const float* __restrict__ bias, int V, int ntiles,
                   const int* __restrict__ rowidx,
                   const int* __restrict__ cnt_ptr,
                   float* __restrict__ partials,
                   float* __restrict__ gathered,
                   const int* __restrict__ target, int glo) {
  constexpr int NC = KT / 32;
  __shared__ __align__(16) unsigned short Ws[NC][128 * 32];
  __shared__ __align__(16) unsigned short As[NC][128 * 32];
  __shared__ float red[2][128];

  const int tn = blockIdx.x, n0 = tn * 128;
  const int Meff = *cnt_ptr;
  const int tid = threadIdx.x, wid = tid >> 6, lane = tid & 63;
  const int quad = lane >> 4, l16 = lane & 15;
  const int wr = wid >> 1, wc = wid & 1;
  const int srow = wid * 32 + (lane >> 2);
  const int skk  = (lane & 3) * 8;

  int wrow0 = n0 + srow;      if (wrow0 > V - 1) wrow0 = V - 1;
  int wrow1 = n0 + srow + 16; if (wrow1 > V - 1) wrow1 = V - 1;
#pragma unroll
  for (int c = 0; c < NC; ++c) {
    gl_lds16(W + (size_t)wrow0 * KT + c * 32 + skk, Ws[c] + wid * 1024);
    gl_lds16(W + (size_t)wrow1 * KT + c * 32 + skk, Ws[c] + wid * 1024 + 512);
  }

  int nj[4]; float bj[4];
#pragma unroll
  for (int j = 0; j < 4; ++j) {
    nj[j] = n0 + wc * 64 + j * 16 + l16;
    bj[j] = (nj[j] < V) ? bias[nj[j]] : 0.f;
  }

  const int nm = (Meff + 127) >> 7;
  for (int m = 0; m < nm; ++m) {
    const int m0 = m * 128;
    int ar0 = m0 + srow;      if (ar0 > Meff - 1) ar0 = Meff - 1;
    int ar1 = m0 + srow + 16; if (ar1 > Meff - 1) ar1 = Meff - 1;
    ar0 = rowidx[ar0]; ar1 = rowidx[ar1];
#pragma unroll
    for (int c = 0; c < NC; ++c) {
      gl_lds16(A + (size_t)ar0 * ldA + c * 32 + skk, As[c] + wid * 1024);
      gl_lds16(A + (size_t)ar1 * ldA + c * 32 + skk, As[c] + wid * 1024 + 512);
    }
    __syncthreads();

    f32x4_t acc[4][4];
    const f32x4_t zero4 = {0.f, 0.f, 0.f, 0.f};
#pragma unroll
    for (int i = 0; i < 4; ++i)
#pragma unroll
      for (int j = 0; j < 4; ++j) acc[i][j] = zero4;
#pragma unroll
    for (int c = 0; c < NC; ++c) {
      bf16x8_t af[4], bfr[4];
#pragma unroll
      for (int i = 0; i < 4; ++i)
        af[i] = *(const bf16x8_t*)(As[c] + (size_t)(wr * 64 + i * 16 + l16) * 32 + quad * 8);
#pragma unroll
      for (int j = 0; j < 4; ++j)
        bfr[j] = *(const bf16x8_t*)(Ws[c] + (size_t)(wc * 64 + j * 16 + l16) * 32 + quad * 8);
#pragma unroll
      for (int i = 0; i < 4; ++i)
#pragma unroll
        for (int j = 0; j < 4; ++j)
          acc[i][j] = __builtin_amdgcn_mfma_f32_16x16x32_bf16(af[i], bfr[j], acc[i][j], 0, 0, 0);
    }

#pragma unroll
    for (int i = 0; i < 4; ++i) {
#pragma unroll
      for (int r = 0; r < 4; ++r) {
        const int row = wr * 64 + i * 16 + quad * 4 + r;
        const int gr = m0 + row;
        const int grc = (gr < Meff) ? gr : (Meff - 1);
        const int token = rowidx[grc];
        float v[4], sum = 0.f;
#pragma unroll
        for (int j = 0; j < 4; ++j) {
          v[j] = acc[i][j][r] + bj[j];
          if (nj[j] < V) sum += __expf(v[j]);
        }
#pragma unroll
        for (int off = 1; off < 16; off <<= 1)
          sum += __shfl_xor(sum, off, 64);
        if (l16 == 0) red[wc][row] = sum;
        const int gi = target[token] - glo;
#pragma unroll
        for (int j = 0; j < 4; ++j)
          if (nj[j] == gi) gathered[token] = v[j];
      }
    }
    __syncthreads();
    if (tid < 128 && (m0 + tid) < Meff)
      partials[(size_t)(m0 + tid) * ntiles + tn] = red[0][tid] + red[1][tid];
  }
}

// ---------------- combine: wave per token ----------------
__global__ __launch_bounds__(256)
void combine_k(const float* __restrict__ part0,
               const float* __restrict__ part1, int nt1,
               const float* __restrict__ part2, int nt2,
               const float* __restrict__ g0, const float* __restrict__ g1,
               const float* __restrict__ g2, const float* __restrict__ cg,
               const int* __restrict__ pos1, const int* __restrict__ pos2,
               const int* __restrict__ target, float* __restrict__ out) {
  const int w = threadIdx.x >> 6, lane = threadIdx.x & 63;
  const int token = blockIdx.x * 4 + w;
  const int t = target[token];

  float S = 0.f;
  for (int i = lane; i < 79; i += 64)
    S += part0[(size_t)token * 79 + i];
#pragma unroll
  for (int off = 1; off < 64; off <<= 1)
    S += __shfl_xor(S, off, 64);
  const float lse_head = __logf(S);

  float res;
  if (t < 20000) {
    res = lse_head - g0[token];
  } else {
    const float* pt; int nt; float gv, ch; int row;
    if (t < 50000) { pt = part1; nt = nt1; gv = g1[token]; ch = cg[2 * token + 1]; row = pos1[token]; }
    else           { pt = part2; nt = nt2; gv = g2[token]; ch = cg[2 * token];     row = pos2[token]; }
    float S2 = 0.f;
    for (int i = lane; i < nt; i += 64)
      S2 += pt[(size_t)row * nt + i];
#pragma unroll
    for (int off = 1; off < 64; off <<= 1)
      S2 += __shfl_xor(S2, off, 64);
    float lse_t = __logf(S2);
    res = -((ch - lse_head) + (gv - lse_t));
  }
  if (lane == 0) out[token] = res;
}

extern "C" void kernel_launch(void* const* d_in, const int* in_sizes, int n_in,
                              void* d_out, int out_size, void* d_ws, size_t ws_size,
                              hipStream_t stream) {
  (void)in_sizes; (void)n_in; (void)out_size; (void)ws_size;
  const float* hidden = (const float*)d_in[0];
  const int*   target = (const int*)d_in[1];
  const float* w0     = (const float*)d_in[2];
  const float* b0     = (const float*)d_in[3];
  const float* cw     = (const float*)d_in[4];
  const float* cb     = (const float*)d_in[5];
  const float* proj0  = (const float*)d_in[6];
  const float* w1     = (const float*)d_in[7];
  const float* b1     = (const float*)d_in[8];
  const float* proj1  = (const float*)d_in[9];
  const float* w2     = (const float*)d_in[10];
  const float* b2     = (const float*)d_in[11];
  const float* proj2  = (const float*)d_in[12];
  float* out = (float*)d_out;

  const int NT1 = 235, NT2 = 391;

  char* p = (char*)d_ws;
  auto alloc = [&](size_t bytes) {
    char* r = p; p += (bytes + 255) & ~(size_t)255; return r;
  };
  unsigned short* Hb   = (unsigned short*)alloc(2048ull * 1024 * 2);
  unsigned short* pAll = (unsigned short*)alloc(1344ull * 1024 * 2);
  unsigned short* w0b  = (unsigned short*)alloc(20002ull * 1024 * 2);
  unsigned short* w1b  = (unsigned short*)alloc(30000ull * 256 * 2);
  unsigned short* w2b  = (unsigned short*)alloc(50000ull * 64 * 2);
  unsigned short* Pall = (unsigned short*)alloc(2048ull * 1344 * 2);
  float* part0 = (float*)alloc(2048ull * 79 * 4);
  float* part1 = (float*)alloc(2048ull * NT1 * 4);
  float* part2 = (float*)alloc(2048ull * NT2 * 4);
  float* g0 = (float*)alloc(2048 * 4);
  float* g1 = (float*)alloc(2048 * 4);
  float* g2 = (float*)alloc(2048 * 4);
  float* cg = (float*)alloc(2048 * 2 * 4);
  int* idx1 = (int*)alloc(2048 * 4);
  int* pos1 = (int*)alloc(2048 * 4);
  int* idx2 = (int*)alloc(2048 * 4);
  int* pos2 = (int*)alloc(2048 * 4);
  int* cnts = (int*)alloc(2 * 4);

  const int c_h = 2048 * 1024 / 4, c_w0 = 20000 * 1024 / 4, c_cw = 2048 / 4,
            c_w1 = 30000 * 256 / 4, c_w2 = 50000 * 64 / 4;
  const int ctot = c_h + c_w0 + c_cw + c_w1 + c_w2;
  const int nb_cast = (ctot + 255) / 256;
  prep_k<<<1 + 1344 + nb_cast, 256, 0, stream>>>(
      target, idx1, pos1, idx2, pos2, cnts,
      proj0, proj1, proj2, pAll,
      hidden, Hb, c_h,
      w0, w0b, c_w0,
      cw, w0b + 20000ull * 1024, c_cw,
      w1, w1b, c_w1,
      w2, w2b, c_w2);

  // merged projections: Pall[2048,1344] = Hb @ pAll^T
  proj_gemm_k<<<dim3(16, 11), 256, 0, stream>>>(Hb, pAll, Pall);

  // head: 256^2 8-phase pipelined GEMM, grid = 8 m-tiles x 79 stripes
  head256_k<<<632, 512, 0, stream>>>(Pall, w0b, b0, cb, part0, g0, cg, target);

  // tails: one block per stripe, W persistent in LDS, m-loop inside
  tail_stripe_k<256><<<NT1, 256, 0, stream>>>(
      Pall + 1024, 1344, w1b, b1, 30000, NT1, idx1, cnts + 0,
      part1, g1, target, 20000);
  tail_stripe_k<64><<<NT2, 256, 0, stream>>>(
      Pall + 1280, 1344, w2b, b2, 50000, NT2, idx2, cnts + 1,
      part2, g2, target, 50000);

  combine_k<<<512, 256, 0, stream>>>(part0, part1, NT1, part2, NT2,
      g0, g1, g2, cg, pos1, pos2, target, out);
}